// Round 3
// baseline (234.258 us; speedup 1.0000x reference)
//
#include <hip/hip_runtime.h>
#include <stdint.h>

// DetectionBaseline: SSD post-process.
// R3: sort-once + 64-wide chunked greedy NMS (exact), replacing the 200-step argmin loop.
// Inputs: locs [16,1280,4] f32, scores [16,1280,21] f32, anchors [1280,4] f32, top_k(=200).
// Output (flat f32): boxes [16,200,4] | labels [16,200] (as float) | scores [16,200].
// ws: uint64 keys [16][20][200] = 512000 bytes (per-class kept lists, ascending key = desc score).

#define A_N     1280
#define CF      20
#define NC      21
#define B_N     16
#define TOPK    200
#define THREADS 256
#define SORT_N  2048

static __device__ __forceinline__ uint64_t pack_key(float sc, uint32_t idx) {
    // softmax scores positive -> float bits monotone. ~bits => ascending key = descending
    // score; low 32 bits = index => ties break toward smaller index (stable argsort / top_k).
    return ((uint64_t)(uint32_t)(~__float_as_uint(sc)) << 32) | (uint64_t)idx;
}

static __device__ __forceinline__ bool iou_gt(const float4 a, const float aarea,
                                              const float4 b, const float barea) {
    // ref-exact: inter/(area_a+area_b-inter) > 0.45
    const float lx = fmaxf(a.x, b.x);
    const float ly = fmaxf(a.y, b.y);
    const float rx = fminf(a.z, b.z);
    const float ry = fminf(a.w, b.w);
    const float wx = fmaxf(rx - lx, 0.0f);
    const float wy = fmaxf(ry - ly, 0.0f);
    const float inter = wx * wy;
    const float uni   = aarea + barea - inter;
    return inter / uni > 0.45f;
}

static __device__ __forceinline__ float box_area(const float4 v) {
    return (v.z - v.x) * (v.w - v.y);
}

__global__ __launch_bounds__(THREADS)
void nms_kernel(const float* __restrict__ locs,
                const float* __restrict__ scores,
                const float* __restrict__ anchors,
                uint64_t* __restrict__ ws_keys)
{
    __shared__ uint64_t      skeys[SORT_N];   // 16 KB sorted (score desc, idx asc) keys
    __shared__ float4        sbox[A_N];       // 20 KB decoded boxes by anchor idx
    __shared__ float4        schunk[64];      // current chunk boxes in rank order
    __shared__ uint64_t      srow[64];        // intra-chunk IoU row masks
    __shared__ float4        swbox[TOPK];     // accepted winner boxes
    __shared__ uint64_t      swkey[TOPK];     // accepted winner keys (rank order)
    __shared__ unsigned char ssupz[64];       // chunk boxes suppressed by prior winners
    __shared__ int           sW;

    const int blk = blockIdx.x;
    const int b   = blk / CF;
    const int c   = blk % CF + 1;             // class channel 1..20
    const int t   = threadIdx.x;

    // ---- decode boxes + softmax + key build ----
    #pragma unroll
    for (int i = 0; i < A_N / THREADS; ++i) {
        const int a = t + i * THREADS;
        const float4 lc = ((const float4*)locs)[(size_t)b * A_N + a];
        const float4 an = ((const float4*)anchors)[a];
        const float cx = lc.x * an.z / 10.0f + an.x;
        const float cy = lc.y * an.w / 10.0f + an.y;
        const float w  = expf(lc.z / 5.0f) * an.z;
        const float h  = expf(lc.w / 5.0f) * an.w;
        float4 v;
        v.x = cx - w / 2.0f; v.y = cy - h / 2.0f;
        v.z = cx + w / 2.0f; v.w = cy + h / 2.0f;
        sbox[a] = v;

        const float* sp = scores + ((size_t)b * A_N + a) * NC;
        float m = sp[0];
        #pragma unroll
        for (int k = 1; k < NC; ++k) m = fmaxf(m, sp[k]);
        float sum = 0.0f;
        #pragma unroll
        for (int k = 0; k < NC; ++k) sum += expf(sp[k] - m);
        const float sc = expf(sp[c] - m) / sum;
        skeys[a] = (sc > 0.01f) ? pack_key(sc, (uint32_t)a) : ~0ull;  // invalid never active/kept
    }
    for (int i = A_N + t; i < SORT_N; i += THREADS) skeys[i] = ~0ull;
    if (t == 0) sW = 0;

    // ---- bitonic sort ascending (R1-verified) ----
    for (int kk = 2; kk <= SORT_N; kk <<= 1)
        for (int j = kk >> 1; j > 0; j >>= 1) {
            __syncthreads();
            for (int i = t; i < SORT_N; i += THREADS) {
                const int ixj = i ^ j;
                if (ixj > i) {
                    const uint64_t a0 = skeys[i], a1 = skeys[ixj];
                    const bool up = ((i & kk) == 0);
                    if ((a0 > a1) == up) { skeys[i] = a1; skeys[ixj] = a0; }
                }
            }
        }
    __syncthreads();

    // ---- chunked greedy NMS: 64 ranks per phase ----
    int W = 0;
    for (int cb = 0; cb < SORT_N; cb += 64) {
        if (skeys[cb] == ~0ull) break;        // uniform: rest of ranks invalid

        // phase A: gather chunk boxes
        if (t < 64) {
            const uint64_t k = skeys[cb + t];
            schunk[t] = (k != ~0ull) ? sbox[(uint32_t)k] : make_float4(0.f, 0.f, 0.f, 0.f);
        }
        __syncthreads();

        // phase B: cross-test vs prior winners + intra-chunk 64x64 row masks
        const int r = t >> 2, q = t & 3;      // 4 threads per chunk box
        const float4 br  = schunk[r];
        const float  arr = box_area(br);
        int sup = (skeys[cb + r] == ~0ull) ? 1 : 0;
        for (int w = q; w < W; w += 4) {
            const float4 bw = swbox[w];
            if (iou_gt(bw, box_area(bw), br, arr)) sup = 1;
        }
        uint64_t part = 0;
        #pragma unroll
        for (int jj = 0; jj < 16; ++jj) {
            const int j = q * 16 + jj;
            const float4 bj = schunk[j];
            if (iou_gt(br, arr, bj, box_area(bj))) part |= (1ull << j);
        }
        // combine the 4 partials (adjacent lanes) -> q==0 lane
        {
            uint32_t lo = (uint32_t)part, hi = (uint32_t)(part >> 32);
            lo |= __shfl_xor(lo, 1, 64); hi |= __shfl_xor(hi, 1, 64);
            lo |= __shfl_xor(lo, 2, 64); hi |= __shfl_xor(hi, 2, 64);
            part = ((uint64_t)hi << 32) | lo;
        }
        sup |= __shfl_xor(sup, 1, 64);
        sup |= __shfl_xor(sup, 2, 64);
        if (q == 0) { srow[r] = part; ssupz[r] = (unsigned char)sup; }
        __syncthreads();

        // phase C: wave 0 resolves the chunk in rank order (registers + ballot/shfl)
        if (t < 64) {
            const uint64_t myrow = srow[t];
            const uint64_t kc    = skeys[cb + t];
            bool alive = (!ssupz[t]) && (kc != ~0ull);
            int Wl = W;
            while (true) {
                const unsigned long long bal = __ballot(alive);
                if (!bal) break;
                const int f = __ffsll(bal) - 1;          // next winner (rank order)
                if (t == f) { swkey[Wl] = kc; swbox[Wl] = schunk[t]; }
                const uint32_t rl = __shfl((uint32_t)myrow, f, 64);
                const uint32_t rh = __shfl((uint32_t)(myrow >> 32), f, 64);
                const uint64_t rowf = ((uint64_t)rh << 32) | rl;
                alive = alive && !((rowf >> t) & 1);     // winner self-clears (IoU=1)
                ++Wl;
                if (Wl >= TOPK) break;                   // cap: later winners can't matter
            }
            if (t == 0) sW = Wl;
        }
        __syncthreads();
        W = sW;
        if (W >= TOPK) break;
    }

    // ---- write per-class kept list (already rank-sorted) ----
    const uint32_t  base = (uint32_t)(c - 1) * A_N;
    uint64_t* const out  = ws_keys + ((size_t)b * CF + (c - 1)) * TOPK;
    for (int k = t; k < TOPK; k += THREADS) {
        if (k < W) {
            const uint64_t kk = swkey[k];
            out[k] = (kk & 0xFFFFFFFF00000000ull) | (uint64_t)(base + (uint32_t)kk);
        } else {
            out[k] = ~0ull;
        }
    }
}

// Per batch: top-200 of 20 sorted 200-lists via truncated pairwise bitonic merges (R2-verified).
__global__ __launch_bounds__(THREADS)
void merge_kernel(const float* __restrict__ locs,
                  const float* __restrict__ anchors,
                  const uint64_t* __restrict__ ws_keys,
                  float* __restrict__ out)
{
    __shared__ uint64_t Abuf[20][256];   // 40 KB
    __shared__ uint64_t Bbuf[10][256];   // 20 KB

    const int b = blockIdx.x;
    const int t = threadIdx.x;
    const uint64_t* const in = ws_keys + (size_t)b * CF * TOPK;

    for (int e = t; e < CF * 256; e += THREADS) {
        const int c = e >> 8, i = e & 255;
        Abuf[c][i] = (i < TOPK) ? in[c * TOPK + i] : ~0ull;
    }

    uint64_t (*src)[256] = Abuf;
    uint64_t (*dst)[256] = Bbuf;
    int n = CF;
    while (n > 1) {
        const int  nm    = n >> 1;
        const bool carry = (n & 1) != 0;
        __syncthreads();
        for (int e = t; e < nm * 256; e += THREADS) {
            const int mm = e >> 8, i = e & 255;
            const uint64_t x = src[2 * mm][i];
            const uint64_t y = src[2 * mm + 1][255 - i];
            dst[mm][i] = x < y ? x : y;              // lower-half extraction (bitonic)
        }
        if (carry)
            for (int i = t; i < 256; i += THREADS) dst[nm][i] = src[n - 1][i];
        for (int j = 128; j; j >>= 1) {
            __syncthreads();
            for (int pp = t; pp < nm * 128; pp += THREADS) {
                const int mm = pp >> 7, qq = pp & 127;
                const int i  = ((qq & ~(j - 1)) << 1) | (qq & (j - 1));
                const uint64_t x = dst[mm][i], y = dst[mm][i + j];
                if (y < x) { dst[mm][i] = y; dst[mm][i + j] = x; }
            }
        }
        uint64_t (*tmp)[256] = src; src = dst; dst = tmp;
        n = nm + (carry ? 1 : 0);
    }
    __syncthreads();

    if (t < TOPK) {
        const uint64_t k = src[0][t];
        float* const boxes_out  = out;                           // [B][TOPK][4]
        float* const labels_out = out + (size_t)B_N * TOPK * 4;  // [B][TOPK]
        float* const scores_out = out + (size_t)B_N * TOPK * 5;  // [B][TOPK]
        const size_t s = (size_t)b * TOPK + t;
        if (k == ~0ull) {
            boxes_out[s * 4 + 0] = 0.0f;
            boxes_out[s * 4 + 1] = 0.0f;
            boxes_out[s * 4 + 2] = 0.0f;
            boxes_out[s * 4 + 3] = 0.0f;
            labels_out[s] = 0.0f;
            scores_out[s] = 0.0f;
        } else {
            const uint32_t flat = (uint32_t)k;
            const int cls = flat / A_N;          // 0..19
            const int a   = flat - cls * A_N;
            const float sc = __uint_as_float(~(uint32_t)(k >> 32));
            const float4 lc = ((const float4*)locs)[(size_t)b * A_N + a];
            const float4 an = ((const float4*)anchors)[a];
            const float cx = lc.x * an.z / 10.0f + an.x;
            const float cy = lc.y * an.w / 10.0f + an.y;
            const float w  = expf(lc.z / 5.0f) * an.z;
            const float h  = expf(lc.w / 5.0f) * an.w;
            boxes_out[s * 4 + 0] = cx - w / 2.0f;
            boxes_out[s * 4 + 1] = cy - h / 2.0f;
            boxes_out[s * 4 + 2] = cx + w / 2.0f;
            boxes_out[s * 4 + 3] = cy + h / 2.0f;
            labels_out[s] = (float)(cls + 1);
            scores_out[s] = sc;
        }
    }
}

extern "C" void kernel_launch(void* const* d_in, const int* in_sizes, int n_in,
                              void* d_out, int out_size, void* d_ws, size_t ws_size,
                              hipStream_t stream) {
    const float* locs    = (const float*)d_in[0];
    const float* scores  = (const float*)d_in[1];
    const float* anchors = (const float*)d_in[2];
    // d_in[3] = top_k (always 200 per setup_inputs)
    uint64_t* ws   = (uint64_t*)d_ws;    // 512000 bytes used
    float*    outp = (float*)d_out;      // 19200 floats

    hipLaunchKernelGGL(nms_kernel,   dim3(B_N * CF), dim3(THREADS), 0, stream,
                       locs, scores, anchors, ws);
    hipLaunchKernelGGL(merge_kernel, dim3(B_N),      dim3(THREADS), 0, stream,
                       locs, anchors, ws, outp);
}